// Round 1
// baseline (389.459 us; speedup 1.0000x reference)
//
#include <hip/hip_runtime.h>
#include <math.h>

#define HDIM 4096
#define NEXP 64
#define NTOK 8192

// ---------------------------------------------------------------------------
// Kernel 1: logits[t][e] += hidden[t][:] . gate_w[e][:]   (fp32, vector ALU)
// grid = (64 M-tiles of 128 tokens, 8 K-splits of 512), block = 256 threads.
// Double-buffered LDS, per-thread 4(M)x8(N) register tile -> 32 FMA per
// k-step vs 3 ds_read_b128 (VALU-bound inner loop). K-split combined via
// fp32 atomicAdd into the zeroed logits buffer (keeps ws footprint at 2 MB
// and shortens sequential accumulation chains for accuracy).
// ---------------------------------------------------------------------------
__global__ __launch_bounds__(256) void gemm_k(const float* __restrict__ A,
                                              const float* __restrict__ W,
                                              float* __restrict__ L) {
  // padded strides (132, 68) keep float4 alignment and <=2-way bank aliasing
  __shared__ __align__(16) float As[2][32 * 132];
  __shared__ __align__(16) float Bs[2][32 * 68];
  const int tid = threadIdx.x;
  const int m_base = blockIdx.x * 128;
  const int k_base = blockIdx.y * 512;
  const int tx = tid & 31, ty = tid >> 5;
  const int m0 = tx * 4, n0 = ty * 8;
  const int sr = tid >> 3;  // staging row 0..31
  const int sc4 = tid & 7;  // staging float4-col 0..7

  const float* Ap = A + (size_t)(m_base + sr) * HDIM + k_base + sc4 * 4;
  const float* Wp = W + (size_t)sr * HDIM + k_base + sc4 * 4;

  float4 ra[4], rb[2];
  float acc[4][8];
#pragma unroll
  for (int i = 0; i < 4; ++i)
#pragma unroll
    for (int j = 0; j < 8; ++j) acc[i][j] = 0.f;

  auto load_tile = [&](int kk) {
#pragma unroll
    for (int t = 0; t < 4; ++t)
      ra[t] = *(const float4*)(Ap + (size_t)t * 32 * HDIM + kk);
#pragma unroll
    for (int t = 0; t < 2; ++t)
      rb[t] = *(const float4*)(Wp + (size_t)t * 32 * HDIM + kk);
  };
  auto store_tile = [&](int buf) {
#pragma unroll
    for (int t = 0; t < 4; ++t) {
      const float v[4] = {ra[t].x, ra[t].y, ra[t].z, ra[t].w};
#pragma unroll
      for (int j = 0; j < 4; ++j)
        As[buf][(sc4 * 4 + j) * 132 + sr + t * 32] = v[j];
    }
#pragma unroll
    for (int t = 0; t < 2; ++t) {
      const float v[4] = {rb[t].x, rb[t].y, rb[t].z, rb[t].w};
#pragma unroll
      for (int j = 0; j < 4; ++j)
        Bs[buf][(sc4 * 4 + j) * 68 + sr + t * 32] = v[j];
    }
  };

  load_tile(0);
  store_tile(0);
  __syncthreads();

  const int NITER = 512 / 32;  // 16
  for (int it = 0; it < NITER; ++it) {
    const int cur = it & 1;
    if (it + 1 < NITER) load_tile((it + 1) * 32);  // global prefetch in-flight
#pragma unroll
    for (int k = 0; k < 32; ++k) {
      const float4 a = *(const float4*)&As[cur][k * 132 + m0];
      const float4 b0 = *(const float4*)&Bs[cur][k * 68 + n0];
      const float4 b1 = *(const float4*)&Bs[cur][k * 68 + n0 + 4];
      const float av[4] = {a.x, a.y, a.z, a.w};
      const float bv[8] = {b0.x, b0.y, b0.z, b0.w, b1.x, b1.y, b1.z, b1.w};
#pragma unroll
      for (int i = 0; i < 4; ++i)
#pragma unroll
        for (int j = 0; j < 8; ++j)
          acc[i][j] = fmaf(av[i], bv[j], acc[i][j]);
    }
    if (it + 1 < NITER) store_tile(cur ^ 1);
    __syncthreads();
  }

#pragma unroll
  for (int i = 0; i < 4; ++i)
#pragma unroll
    for (int j = 0; j < 8; ++j)
      atomicAdd(&L[(size_t)(m_base + m0 + i) * NEXP + n0 + j], acc[i][j]);
}

// ---------------------------------------------------------------------------
// Kernel 2: per-token softmax + top-8 (desc, lowest-index tie-break like
// lax.top_k) + normalized weights + aux-loss partials.
// One wave per token (lane = expert), 8 tokens per wave; 256 blocks x 4 waves.
// ---------------------------------------------------------------------------
__global__ __launch_bounds__(256) void router_k(const float* __restrict__ L,
                                                float* __restrict__ out,
                                                float* __restrict__ auxbuf) {
  __shared__ float s_aux[128];  // [0:64) sum of probs, [64:128) pick counts
  const int tid = threadIdx.x;
  if (tid < 128) s_aux[tid] = 0.f;
  __syncthreads();
  const int lane = tid & 63;
  const int w = tid >> 6;
#pragma unroll 1
  for (int rep = 0; rep < 8; ++rep) {
    const int t = (blockIdx.x * 4 + w) * 8 + rep;
    const float logit = L[t * 64 + lane];
    float mx = logit;
#pragma unroll
    for (int off = 32; off >= 1; off >>= 1)
      mx = fmaxf(mx, __shfl_xor(mx, off, 64));
    const float e = expf(logit - mx);
    float s = e;
#pragma unroll
    for (int off = 32; off >= 1; off >>= 1) s += __shfl_xor(s, off, 64);
    const float prob = e / s;
    atomicAdd(&s_aux[lane], prob);

    float v = prob;   // remaining candidate value (prob > 0 always)
    float myw = 0.f;  // weight this lane will write (lane j holds rank j)
    int myi = 0;
    float tot = 0.f;
#pragma unroll
    for (int j = 0; j < 8; ++j) {
      float bv = v;
      int bi = lane;
#pragma unroll
      for (int off = 32; off >= 1; off >>= 1) {
        const float ov = __shfl_xor(bv, off, 64);
        const int oi = __shfl_xor(bi, off, 64);
        if (ov > bv || (ov == bv && oi < bi)) { bv = ov; bi = oi; }
      }
      tot += bv;
      if (lane == j) { myw = bv; myi = bi; }
      if (lane == bi) v = -1.f;  // remove winner
    }
    if (v < 0.f) atomicAdd(&s_aux[64 + lane], 1.f);  // this expert was picked
    if (lane < 8) {
      out[t * 8 + lane] = myw / tot;                    // normalized weight
      out[NTOK * 8 + t * 8 + lane] = (float)myi;        // index as float
    }
  }
  __syncthreads();
  if (tid < 128) atomicAdd(&auxbuf[tid], s_aux[tid]);
}

// ---------------------------------------------------------------------------
// Kernel 3: aux = E * sum_e (count_e/(T*K)) * (sumprob_e/T)
// ---------------------------------------------------------------------------
__global__ void aux_k(const float* __restrict__ auxbuf, float* __restrict__ out) {
  const int e = threadIdx.x;  // 64 threads
  const float p = auxbuf[e] * (1.f / (float)NTOK);
  const float f = auxbuf[64 + e] * (1.f / ((float)NTOK * 8.f));
  float v = f * p;
#pragma unroll
  for (int off = 32; off >= 1; off >>= 1) v += __shfl_xor(v, off, 64);
  if (e == 0) out[2 * NTOK * 8] = 64.f * v;
}

extern "C" void kernel_launch(void* const* d_in, const int* in_sizes, int n_in,
                              void* d_out, int out_size, void* d_ws, size_t ws_size,
                              hipStream_t stream) {
  const float* hidden = (const float*)d_in[0];  // 8192 x 4096 fp32
  const float* gate = (const float*)d_in[1];    // 64 x 4096 fp32
  float* out = (float*)d_out;                   // [w 65536 | idx 65536 | aux 1]
  float* ws = (float*)d_ws;
  float* logits = ws;               // 8192*64 fp32 = 2 MB
  float* auxbuf = ws + NTOK * NEXP; // 128 fp32

  hipMemsetAsync(d_ws, 0, (NTOK * NEXP + 128) * sizeof(float), stream);
  gemm_k<<<dim3(64, 8), 256, 0, stream>>>(hidden, gate, logits);
  router_k<<<256, 256, 0, stream>>>(logits, out, auxbuf);
  aux_k<<<1, 64, 0, stream>>>(auxbuf, out);
}

// Round 2
// 341.874 us; speedup vs baseline: 1.1392x; 1.1392x over previous
//
#include <hip/hip_runtime.h>
#include <math.h>

#define HDIM 4096
#define NEXP 64
#define NTOK 8192
#define KSPLIT 8
#define KSLICE (HDIM / KSPLIT)   // 512
#define BM 128
#define CHUNK 32
#define NCHUNK (KSLICE / CHUNK)  // 16
#define ASTRIDE 40               // shorts per LDS row (32 + 8 pad -> 2-way max bank aliasing)
#define SLICEOFF 256             // floats: auxbuf lives at ws[0..255]

typedef short short8 __attribute__((ext_vector_type(8)));
typedef float f32x4 __attribute__((ext_vector_type(4)));

// Exact 3-way bf16 split of two fp32 values, packed as (lo16=x0, hi16=x1).
// x = hi + mid + lo exactly (8+8+8 mantissa bits covers fp32's 24).
__device__ __forceinline__ void split2x3(float x0, float x1, int& h, int& md, int& lo) {
  unsigned u0 = __float_as_uint(x0), u1 = __float_as_uint(x1);
  unsigned h0 = u0 & 0xFFFF0000u, h1 = u1 & 0xFFFF0000u;
  float r0 = x0 - __uint_as_float(h0);
  float r1 = x1 - __uint_as_float(h1);
  unsigned m0 = __float_as_uint(r0) & 0xFFFF0000u;
  unsigned m1 = __float_as_uint(r1) & 0xFFFF0000u;
  float s0 = r0 - __uint_as_float(m0);
  float s1 = r1 - __uint_as_float(m1);
  h  = (int)((h0 >> 16) | h1);
  md = (int)((m0 >> 16) | m1);
  lo = (int)((__float_as_uint(s0) >> 16) | (__float_as_uint(s1) & 0xFFFF0000u));
}

// ---------------------------------------------------------------------------
// GEMM: logits[t][e] = hidden[t][:] . gate_w[e][:] via bf16x3-split MFMA.
// Block: 256 thr (4 waves), tile M=128 x N=64, K-slice 512 in chunks of 32.
// Per chunk: stage fp32 -> exact hi/mid/lo bf16 in LDS, then 6 MFMA terms
// (hh, hm, mh, hl, lh, mm; dropped terms are O(2^-24)). Non-atomic mode
// stores partials to slice blockIdx.y (summed by topk_k).
// ---------------------------------------------------------------------------
__global__ __launch_bounds__(256, 3) void gemm_k(const float* __restrict__ A,
                                                 const float* __restrict__ W,
                                                 float* __restrict__ Lp,
                                                 int atomic_mode) {
  __shared__ __align__(16) short Ah[BM * ASTRIDE], Amid[BM * ASTRIDE], Alo[BM * ASTRIDE];
  __shared__ __align__(16) short Bh[NEXP * ASTRIDE], Bmid[NEXP * ASTRIDE], Blo[NEXP * ASTRIDE];
  const int tid = threadIdx.x;
  const int m_base = blockIdx.x * BM;
  const int k_base = blockIdx.y * KSLICE;
  float* Lout = Lp + (atomic_mode ? (size_t)0 : (size_t)blockIdx.y * NTOK * NEXP);

  // staging: each thread owns 8 consecutive k of rows (tid>>2), (tid>>2)+64 for A
  // and row (tid>>2) for B; k-group = tid&3.
  const int srow = tid >> 2;
  const int skg = tid & 3;
  const float* gA0 = A + (size_t)(m_base + srow) * HDIM + k_base + skg * 8;
  const float* gA1 = gA0 + (size_t)64 * HDIM;
  const float* gB = W + (size_t)srow * HDIM + k_base + skg * 8;

  const int lane = tid & 63;
  const int wave = tid >> 6;
  const int l15 = lane & 15;
  const int quad = lane >> 4;
  const int wm = wave * 32;  // wave's 32-token m range

  f32x4 acc[2][4];
#pragma unroll
  for (int mt = 0; mt < 2; ++mt)
#pragma unroll
    for (int nt = 0; nt < 4; ++nt) acc[mt][nt] = (f32x4){0.f, 0.f, 0.f, 0.f};

  float4 pa0[2], pa1[2], pb[2];
  auto gload = [&](int i) {
    const float* p = gA0 + i * CHUNK;
    pa0[0] = *(const float4*)(p);
    pa0[1] = *(const float4*)(p + 4);
    p = gA1 + i * CHUNK;
    pa1[0] = *(const float4*)(p);
    pa1[1] = *(const float4*)(p + 4);
    p = gB + i * CHUNK;
    pb[0] = *(const float4*)(p);
    pb[1] = *(const float4*)(p + 4);
  };
  auto convert_store = [&]() {
    const float fa0[8] = {pa0[0].x, pa0[0].y, pa0[0].z, pa0[0].w,
                          pa0[1].x, pa0[1].y, pa0[1].z, pa0[1].w};
    const float fa1[8] = {pa1[0].x, pa1[0].y, pa1[0].z, pa1[0].w,
                          pa1[1].x, pa1[1].y, pa1[1].z, pa1[1].w};
    const float fb[8] = {pb[0].x, pb[0].y, pb[0].z, pb[0].w,
                         pb[1].x, pb[1].y, pb[1].z, pb[1].w};
    int h[4], md[4], lo[4];
    int off = srow * ASTRIDE + skg * 8;
#pragma unroll
    for (int j = 0; j < 4; ++j) split2x3(fa0[2 * j], fa0[2 * j + 1], h[j], md[j], lo[j]);
    *(int4*)&Ah[off] = make_int4(h[0], h[1], h[2], h[3]);
    *(int4*)&Amid[off] = make_int4(md[0], md[1], md[2], md[3]);
    *(int4*)&Alo[off] = make_int4(lo[0], lo[1], lo[2], lo[3]);
#pragma unroll
    for (int j = 0; j < 4; ++j) split2x3(fa1[2 * j], fa1[2 * j + 1], h[j], md[j], lo[j]);
    int off1 = (srow + 64) * ASTRIDE + skg * 8;
    *(int4*)&Ah[off1] = make_int4(h[0], h[1], h[2], h[3]);
    *(int4*)&Amid[off1] = make_int4(md[0], md[1], md[2], md[3]);
    *(int4*)&Alo[off1] = make_int4(lo[0], lo[1], lo[2], lo[3]);
#pragma unroll
    for (int j = 0; j < 4; ++j) split2x3(fb[2 * j], fb[2 * j + 1], h[j], md[j], lo[j]);
    *(int4*)&Bh[off] = make_int4(h[0], h[1], h[2], h[3]);
    *(int4*)&Bmid[off] = make_int4(md[0], md[1], md[2], md[3]);
    *(int4*)&Blo[off] = make_int4(lo[0], lo[1], lo[2], lo[3]);
  };

  gload(0);
  convert_store();
  __syncthreads();

  for (int i = 0; i < NCHUNK; ++i) {
    if (i + 1 < NCHUNK) gload(i + 1);  // prefetch next chunk into regs
    short8 fa[2][3];
#pragma unroll
    for (int mt = 0; mt < 2; ++mt) {
      const int r = (wm + mt * 16 + l15) * ASTRIDE + quad * 8;
      fa[mt][0] = *(const short8*)&Ah[r];
      fa[mt][1] = *(const short8*)&Amid[r];
      fa[mt][2] = *(const short8*)&Alo[r];
    }
#pragma unroll
    for (int nt = 0; nt < 4; ++nt) {
      const int r = (nt * 16 + l15) * ASTRIDE + quad * 8;
      const short8 bh = *(const short8*)&Bh[r];
      const short8 bm = *(const short8*)&Bmid[r];
      const short8 bl = *(const short8*)&Blo[r];
#pragma unroll
      for (int mt = 0; mt < 2; ++mt) {
        f32x4 c = acc[mt][nt];
        c = __builtin_amdgcn_mfma_f32_16x16x32_bf16(fa[mt][0], bh, c, 0, 0, 0);
        c = __builtin_amdgcn_mfma_f32_16x16x32_bf16(fa[mt][0], bm, c, 0, 0, 0);
        c = __builtin_amdgcn_mfma_f32_16x16x32_bf16(fa[mt][1], bh, c, 0, 0, 0);
        c = __builtin_amdgcn_mfma_f32_16x16x32_bf16(fa[mt][0], bl, c, 0, 0, 0);
        c = __builtin_amdgcn_mfma_f32_16x16x32_bf16(fa[mt][2], bh, c, 0, 0, 0);
        c = __builtin_amdgcn_mfma_f32_16x16x32_bf16(fa[mt][1], bm, c, 0, 0, 0);
        acc[mt][nt] = c;
      }
    }
    __syncthreads();                        // all waves done reading LDS
    if (i + 1 < NCHUNK) convert_store();    // overwrite LDS with next chunk
    __syncthreads();
  }

#pragma unroll
  for (int mt = 0; mt < 2; ++mt)
#pragma unroll
    for (int nt = 0; nt < 4; ++nt)
#pragma unroll
      for (int r = 0; r < 4; ++r) {
        const int m = m_base + wm + mt * 16 + quad * 4 + r;
        const int n = nt * 16 + l15;
        if (atomic_mode) atomicAdd(&Lout[(size_t)m * NEXP + n], acc[mt][nt][r]);
        else Lout[(size_t)m * NEXP + n] = acc[mt][nt][r];
      }
}

// ---------------------------------------------------------------------------
// Top-k router: one thread per token, row register-resident. Branchless
// masked argmax x8 (strict >, ascending j => lowest-index tie-break, matching
// lax.top_k stability). Ranking done on logits (softmax is monotone).
// Prob column-sums via LDS transpose; pick counts via global float atomics.
// ---------------------------------------------------------------------------
__global__ __launch_bounds__(64) void topk_k(const float* __restrict__ Lp, int nsl,
                                             float* __restrict__ out,
                                             float* __restrict__ auxbuf) {
  __shared__ float P[64][65];
  const int tid = threadIdx.x;
  const int t = blockIdx.x * 64 + tid;
  float row[64];
#pragma unroll
  for (int j = 0; j < 16; ++j) {
    const float4 v = *(const float4*)&Lp[(size_t)t * NEXP + j * 4];
    row[4 * j + 0] = v.x; row[4 * j + 1] = v.y;
    row[4 * j + 2] = v.z; row[4 * j + 3] = v.w;
  }
  for (int s = 1; s < nsl; ++s) {
#pragma unroll
    for (int j = 0; j < 16; ++j) {
      const float4 v = *(const float4*)&Lp[(size_t)s * NTOK * NEXP + (size_t)t * NEXP + j * 4];
      row[4 * j + 0] += v.x; row[4 * j + 1] += v.y;
      row[4 * j + 2] += v.z; row[4 * j + 3] += v.w;
    }
  }
  float mx = row[0];
#pragma unroll
  for (int j = 1; j < 64; ++j) mx = fmaxf(mx, row[j]);

  float bw[8];
  int bidx[8];
  unsigned long long sel = 0ull;
#pragma unroll
  for (int r = 0; r < 8; ++r) {
    float bv = -3.0e38f;
    int bi = 0;
#pragma unroll
    for (int j = 0; j < 64; ++j) {
      const bool avail = ((sel >> j) & 1ull) == 0ull;
      if (avail && row[j] > bv) { bv = row[j]; bi = j; }
    }
    sel |= (1ull << bi);
    bw[r] = bv;
    bidx[r] = bi;
  }

  float s = 0.f;
#pragma unroll
  for (int j = 0; j < 64; ++j) {
    row[j] = __expf(row[j] - mx);
    s += row[j];
  }
  const float inv = 1.f / s;
#pragma unroll
  for (int j = 0; j < 64; ++j) P[tid][j] = row[j] * inv;

  float tw = 0.f;
  float ew[8];
#pragma unroll
  for (int r = 0; r < 8; ++r) { ew[r] = __expf(bw[r] - mx); tw += ew[r]; }
  const float invw = 1.f / tw;
#pragma unroll
  for (int r = 0; r < 8; ++r) {
    out[(size_t)t * 8 + r] = ew[r] * invw;
    out[(size_t)NTOK * 8 + (size_t)t * 8 + r] = (float)bidx[r];
    atomicAdd(&auxbuf[64 + bidx[r]], 1.0f);  // tokens_per_expert
  }
  __syncthreads();
  float cs = 0.f;
#pragma unroll
  for (int rr = 0; rr < 64; ++rr) cs += P[rr][tid];
  atomicAdd(&auxbuf[tid], cs);  // sum of probs for expert `tid`
}

// aux = E * sum_e (count_e/(T*K)) * (sumprob_e/T)
__global__ void aux_k(const float* __restrict__ auxbuf, float* __restrict__ out) {
  const int e = threadIdx.x;  // 64 threads
  const float p = auxbuf[e] * (1.f / (float)NTOK);
  const float f = auxbuf[64 + e] * (1.f / ((float)NTOK * 8.f));
  float v = f * p;
#pragma unroll
  for (int off = 32; off >= 1; off >>= 1) v += __shfl_xor(v, off, 64);
  if (e == 0) out[2 * NTOK * 8] = 64.f * v;
}

extern "C" void kernel_launch(void* const* d_in, const int* in_sizes, int n_in,
                              void* d_out, int out_size, void* d_ws, size_t ws_size,
                              hipStream_t stream) {
  const float* hidden = (const float*)d_in[0];  // 8192 x 4096 fp32
  const float* gate = (const float*)d_in[1];    // 64 x 4096 fp32
  float* out = (float*)d_out;                   // [w 65536 | idx 65536 | aux 1]
  float* ws = (float*)d_ws;
  float* auxbuf = ws;              // 128 floats used
  float* slices = ws + SLICEOFF;   // KSPLIT x (8192*64) fp32 partials = 16 MB

  const size_t need = (size_t)SLICEOFF * 4 + (size_t)KSPLIT * NTOK * NEXP * 4;
  const int atomic_mode = (ws_size < need) ? 1 : 0;
  const int nsl = atomic_mode ? 1 : KSPLIT;

  if (atomic_mode)
    hipMemsetAsync(d_ws, 0, (size_t)SLICEOFF * 4 + (size_t)NTOK * NEXP * 4, stream);
  else
    hipMemsetAsync(d_ws, 0, (size_t)SLICEOFF * 4, stream);

  gemm_k<<<dim3(64, KSPLIT), 256, 0, stream>>>(hidden, gate, slices, atomic_mode);
  topk_k<<<NTOK / 64, 64, 0, stream>>>(slices, nsl, out, auxbuf);
  aux_k<<<1, 64, 0, stream>>>(auxbuf, out);
}

// Round 3
// 216.264 us; speedup vs baseline: 1.8009x; 1.5808x over previous
//
#include <hip/hip_runtime.h>
#include <math.h>

#define HDIM 4096
#define NEXP 64
#define NTOK 8192
#define KSPLIT 8
#define KSLICE (HDIM / KSPLIT)   // 512
#define BM 128
#define CHUNK 32
#define NCHUNK (KSLICE / CHUNK)  // 16
#define ASTRIDE 40               // shorts per LDS row (uniform bank coverage for b128 ops)
#define SLICEOFF 1024            // floats: 8 auxbuf copies of 128 live at ws[0..1023]
#define TPW 2                    // tokens per wave in topk_k

typedef short short8 __attribute__((ext_vector_type(8)));
typedef float f32x4 __attribute__((ext_vector_type(4)));

// Exact 3-way bf16 split of two fp32 values, packed as (lo16=x0, hi16=x1).
// x = hi + mid + lo exactly (8+8+8 mantissa bits covers fp32's 24).
__device__ __forceinline__ void split2x3(float x0, float x1, int& h, int& md, int& lo) {
  unsigned u0 = __float_as_uint(x0), u1 = __float_as_uint(x1);
  unsigned h0 = u0 & 0xFFFF0000u, h1 = u1 & 0xFFFF0000u;
  float r0 = x0 - __uint_as_float(h0);
  float r1 = x1 - __uint_as_float(h1);
  unsigned m0 = __float_as_uint(r0) & 0xFFFF0000u;
  unsigned m1 = __float_as_uint(r1) & 0xFFFF0000u;
  float s0 = r0 - __uint_as_float(m0);
  float s1 = r1 - __uint_as_float(m1);
  h  = (int)((h0 >> 16) | h1);
  md = (int)((m0 >> 16) | m1);
  lo = (int)((__float_as_uint(s0) >> 16) | (__float_as_uint(s1) & 0xFFFF0000u));
}

// ---------------------------------------------------------------------------
// GEMM: logits[t][e] = hidden[t][:] . gate_w[e][:] via bf16x3-split MFMA.
// (unchanged from round 2 — kept identical for attribution; counters will
// show it at the top of the table now that topk is fast)
// ---------------------------------------------------------------------------
__global__ __launch_bounds__(256, 3) void gemm_k(const float* __restrict__ A,
                                                 const float* __restrict__ W,
                                                 float* __restrict__ Lp,
                                                 int atomic_mode) {
  __shared__ __align__(16) short Ah[BM * ASTRIDE], Amid[BM * ASTRIDE], Alo[BM * ASTRIDE];
  __shared__ __align__(16) short Bh[NEXP * ASTRIDE], Bmid[NEXP * ASTRIDE], Blo[NEXP * ASTRIDE];
  const int tid = threadIdx.x;
  const int m_base = blockIdx.x * BM;
  const int k_base = blockIdx.y * KSLICE;
  float* Lout = Lp + (atomic_mode ? (size_t)0 : (size_t)blockIdx.y * NTOK * NEXP);

  const int srow = tid >> 2;
  const int skg = tid & 3;
  const float* gA0 = A + (size_t)(m_base + srow) * HDIM + k_base + skg * 8;
  const float* gA1 = gA0 + (size_t)64 * HDIM;
  const float* gB = W + (size_t)srow * HDIM + k_base + skg * 8;

  const int lane = tid & 63;
  const int wave = tid >> 6;
  const int l15 = lane & 15;
  const int quad = lane >> 4;
  const int wm = wave * 32;

  f32x4 acc[2][4];
#pragma unroll
  for (int mt = 0; mt < 2; ++mt)
#pragma unroll
    for (int nt = 0; nt < 4; ++nt) acc[mt][nt] = (f32x4){0.f, 0.f, 0.f, 0.f};

  float4 pa0[2], pa1[2], pb[2];
  auto gload = [&](int i) {
    const float* p = gA0 + i * CHUNK;
    pa0[0] = *(const float4*)(p);
    pa0[1] = *(const float4*)(p + 4);
    p = gA1 + i * CHUNK;
    pa1[0] = *(const float4*)(p);
    pa1[1] = *(const float4*)(p + 4);
    p = gB + i * CHUNK;
    pb[0] = *(const float4*)(p);
    pb[1] = *(const float4*)(p + 4);
  };
  auto convert_store = [&]() {
    const float fa0[8] = {pa0[0].x, pa0[0].y, pa0[0].z, pa0[0].w,
                          pa0[1].x, pa0[1].y, pa0[1].z, pa0[1].w};
    const float fa1[8] = {pa1[0].x, pa1[0].y, pa1[0].z, pa1[0].w,
                          pa1[1].x, pa1[1].y, pa1[1].z, pa1[1].w};
    const float fb[8] = {pb[0].x, pb[0].y, pb[0].z, pb[0].w,
                         pb[1].x, pb[1].y, pb[1].z, pb[1].w};
    int h[4], md[4], lo[4];
    int off = srow * ASTRIDE + skg * 8;
#pragma unroll
    for (int j = 0; j < 4; ++j) split2x3(fa0[2 * j], fa0[2 * j + 1], h[j], md[j], lo[j]);
    *(int4*)&Ah[off] = make_int4(h[0], h[1], h[2], h[3]);
    *(int4*)&Amid[off] = make_int4(md[0], md[1], md[2], md[3]);
    *(int4*)&Alo[off] = make_int4(lo[0], lo[1], lo[2], lo[3]);
#pragma unroll
    for (int j = 0; j < 4; ++j) split2x3(fa1[2 * j], fa1[2 * j + 1], h[j], md[j], lo[j]);
    int off1 = (srow + 64) * ASTRIDE + skg * 8;
    *(int4*)&Ah[off1] = make_int4(h[0], h[1], h[2], h[3]);
    *(int4*)&Amid[off1] = make_int4(md[0], md[1], md[2], md[3]);
    *(int4*)&Alo[off1] = make_int4(lo[0], lo[1], lo[2], lo[3]);
#pragma unroll
    for (int j = 0; j < 4; ++j) split2x3(fb[2 * j], fb[2 * j + 1], h[j], md[j], lo[j]);
    *(int4*)&Bh[off] = make_int4(h[0], h[1], h[2], h[3]);
    *(int4*)&Bmid[off] = make_int4(md[0], md[1], md[2], md[3]);
    *(int4*)&Blo[off] = make_int4(lo[0], lo[1], lo[2], lo[3]);
  };

  gload(0);
  convert_store();
  __syncthreads();

  for (int i = 0; i < NCHUNK; ++i) {
    if (i + 1 < NCHUNK) gload(i + 1);
    short8 fa[2][3];
#pragma unroll
    for (int mt = 0; mt < 2; ++mt) {
      const int r = (wm + mt * 16 + l15) * ASTRIDE + quad * 8;
      fa[mt][0] = *(const short8*)&Ah[r];
      fa[mt][1] = *(const short8*)&Amid[r];
      fa[mt][2] = *(const short8*)&Alo[r];
    }
#pragma unroll
    for (int nt = 0; nt < 4; ++nt) {
      const int r = (nt * 16 + l15) * ASTRIDE + quad * 8;
      const short8 bh = *(const short8*)&Bh[r];
      const short8 bm = *(const short8*)&Bmid[r];
      const short8 bl = *(const short8*)&Blo[r];
#pragma unroll
      for (int mt = 0; mt < 2; ++mt) {
        f32x4 c = acc[mt][nt];
        c = __builtin_amdgcn_mfma_f32_16x16x32_bf16(fa[mt][0], bh, c, 0, 0, 0);
        c = __builtin_amdgcn_mfma_f32_16x16x32_bf16(fa[mt][0], bm, c, 0, 0, 0);
        c = __builtin_amdgcn_mfma_f32_16x16x32_bf16(fa[mt][1], bh, c, 0, 0, 0);
        c = __builtin_amdgcn_mfma_f32_16x16x32_bf16(fa[mt][0], bl, c, 0, 0, 0);
        c = __builtin_amdgcn_mfma_f32_16x16x32_bf16(fa[mt][2], bh, c, 0, 0, 0);
        c = __builtin_amdgcn_mfma_f32_16x16x32_bf16(fa[mt][1], bm, c, 0, 0, 0);
        acc[mt][nt] = c;
      }
    }
    __syncthreads();
    if (i + 1 < NCHUNK) convert_store();
    __syncthreads();
  }

#pragma unroll
  for (int mt = 0; mt < 2; ++mt)
#pragma unroll
    for (int nt = 0; nt < 4; ++nt)
#pragma unroll
      for (int r = 0; r < 4; ++r) {
        const int m = m_base + wm + mt * 16 + quad * 4 + r;
        const int n = nt * 16 + l15;
        if (atomic_mode) atomicAdd(&Lout[(size_t)m * NEXP + n], acc[mt][nt][r]);
        else Lout[(size_t)m * NEXP + n] = acc[mt][nt][r];
      }
}

// ---------------------------------------------------------------------------
// Top-k router, wave-per-token (lane = expert). No per-thread row array ->
// no spills. rank_i = #{j: x_j > x_i || (x_j==x_i && j<i)} gives a stable
// permutation (lax.top_k order); winners scatter (prob, index) to lanes 0..7
// via ds_permute. Row broadcast through LDS (conflict-free float4 reads).
// ---------------------------------------------------------------------------
__global__ __launch_bounds__(256) void topk_k(const float* __restrict__ Lp, int nsl,
                                              float* __restrict__ out,
                                              float* __restrict__ auxbuf) {
  __shared__ float sl[4][64];
  __shared__ float s_aux[128];  // [0:64) prob sums, [64:128) pick counts
  const int tid = threadIdx.x;
  const int wave = tid >> 6, lane = tid & 63;
  if (tid < 128) s_aux[tid] = 0.f;
  __syncthreads();

  for (int it = 0; it < TPW; ++it) {
    const int t = (blockIdx.x * 4 + wave) * TPW + it;
    float x = 0.f;
    for (int s = 0; s < nsl; ++s)
      x += Lp[(size_t)s * (NTOK * NEXP) + (size_t)t * NEXP + lane];
    sl[wave][lane] = x;

    float mx = x;
#pragma unroll
    for (int off = 32; off >= 1; off >>= 1)
      mx = fmaxf(mx, __shfl_xor(mx, off, 64));
    const float e = __expf(x - mx);
    float ssum = e;
#pragma unroll
    for (int off = 32; off >= 1; off >>= 1) ssum += __shfl_xor(ssum, off, 64);
    const float prob = e / ssum;

    __syncthreads();  // sl visible (uniform barrier: same trip count all waves)

    int cnt = 0;
#pragma unroll
    for (int c = 0; c < 4; ++c) {
      const float4 v0 = *(const float4*)&sl[wave][c * 16 + 0];
      const float4 v1 = *(const float4*)&sl[wave][c * 16 + 4];
      const float4 v2 = *(const float4*)&sl[wave][c * 16 + 8];
      const float4 v3 = *(const float4*)&sl[wave][c * 16 + 12];
      const float xv[16] = {v0.x, v0.y, v0.z, v0.w, v1.x, v1.y, v1.z, v1.w,
                            v2.x, v2.y, v2.z, v2.w, v3.x, v3.y, v3.z, v3.w};
#pragma unroll
      for (int j = 0; j < 16; ++j) {
        const int jj = c * 16 + j;
        cnt += (xv[j] > x) || (xv[j] == x && jj < lane);
      }
    }

    float tp = (cnt < 8) ? prob : 0.f;
    float tsum = tp;
#pragma unroll
    for (int off = 32; off >= 1; off >>= 1) tsum += __shfl_xor(tsum, off, 64);

    const int dst = cnt << 2;  // ranks are a permutation -> collision-free
    const float pv = __uint_as_float(
        (unsigned)__builtin_amdgcn_ds_permute(dst, (int)__float_as_uint(prob)));
    const int pi = __builtin_amdgcn_ds_permute(dst, lane);
    if (lane < 8) {
      out[(size_t)t * 8 + lane] = pv / tsum;
      out[(size_t)NTOK * 8 + (size_t)t * 8 + lane] = (float)pi;
    }
    atomicAdd(&s_aux[lane], prob);
    if (cnt < 8) atomicAdd(&s_aux[64 + lane], 1.f);
  }
  __syncthreads();
  if (tid < 128) atomicAdd(&auxbuf[(blockIdx.x & 7) * 128 + tid], s_aux[tid]);
}

// aux = E * sum_e (count_e/(T*K)) * (sumprob_e/T), over 8 auxbuf copies
__global__ void aux_k(const float* __restrict__ auxbuf, float* __restrict__ out) {
  const int e = threadIdx.x;  // 64 threads
  float p = 0.f, f = 0.f;
#pragma unroll
  for (int c = 0; c < 8; ++c) {
    p += auxbuf[c * 128 + e];
    f += auxbuf[c * 128 + 64 + e];
  }
  p *= (1.f / (float)NTOK);
  f *= (1.f / ((float)NTOK * 8.f));
  float v = f * p;
#pragma unroll
  for (int off = 32; off >= 1; off >>= 1) v += __shfl_xor(v, off, 64);
  if (e == 0) out[2 * NTOK * 8] = 64.f * v;
}

extern "C" void kernel_launch(void* const* d_in, const int* in_sizes, int n_in,
                              void* d_out, int out_size, void* d_ws, size_t ws_size,
                              hipStream_t stream) {
  const float* hidden = (const float*)d_in[0];  // 8192 x 4096 fp32
  const float* gate = (const float*)d_in[1];    // 64 x 4096 fp32
  float* out = (float*)d_out;                   // [w 65536 | idx 65536 | aux 1]
  float* ws = (float*)d_ws;
  float* auxbuf = ws;              // 8 copies x 128 floats
  float* slices = ws + SLICEOFF;   // KSPLIT x (8192*64) fp32 partials = 16 MB

  const size_t need = (size_t)SLICEOFF * 4 + (size_t)KSPLIT * NTOK * NEXP * 4;
  const int atomic_mode = (ws_size < need) ? 1 : 0;
  const int nsl = atomic_mode ? 1 : KSPLIT;

  if (atomic_mode)
    hipMemsetAsync(d_ws, 0, (size_t)SLICEOFF * 4 + (size_t)NTOK * NEXP * 4, stream);
  else
    hipMemsetAsync(d_ws, 0, (size_t)SLICEOFF * 4, stream);

  gemm_k<<<dim3(64, KSPLIT), 256, 0, stream>>>(hidden, gate, slices, atomic_mode);
  topk_k<<<NTOK / (4 * TPW), 256, 0, stream>>>(slices, nsl, out, auxbuf);
  aux_k<<<1, 64, 0, stream>>>(auxbuf, out);
}